// Round 1
// baseline (1516.866 us; speedup 1.0000x reference)
//
#include <hip/hip_runtime.h>
#include <hip/hip_bf16.h>

// Problem constants
#define NB 16384        // batch rows
#define TEXT_D 768
#define TECH_D 256
#define IND 1024        // IN_D
#define OUTD 1024       // OUT_D
#define NE 8            // experts

typedef unsigned short u16;
typedef __bf16 bf16x8 __attribute__((ext_vector_type(8)));
typedef float f32x4 __attribute__((ext_vector_type(4)));

__device__ __forceinline__ u16 f2bf(float f) {
  union { float f; unsigned int u; } x; x.f = f;
  unsigned int u = x.u;
  return (u16)((u + 0x7FFFu + ((u >> 16) & 1u)) >> 16);
}

__device__ __forceinline__ void gload_lds16(const void* g, void* l) {
  __builtin_amdgcn_global_load_lds(
      (const __attribute__((address_space(1))) unsigned int*)g,
      (__attribute__((address_space(3))) unsigned int*)l, 16, 0, 0);
}

// ---------------------------------------------------------------------------
// Kernel 1: concat(text, tech) -> bf16 xb [NB][IND]
// ---------------------------------------------------------------------------
__global__ __launch_bounds__(256) void convert_x(
    const float* __restrict__ text, const float* __restrict__ tech,
    u16* __restrict__ xb) {
  int idx = (blockIdx.x * 256 + threadIdx.x) * 4;  // element index
  int b = idx >> 10;
  int d = idx & 1023;
  float4 v;
  if (d < TEXT_D) v = *(const float4*)&text[(size_t)b * TEXT_D + d];
  else            v = *(const float4*)&tech[(size_t)b * TECH_D + (d - TEXT_D)];
  ushort4 o = make_ushort4(f2bf(v.x), f2bf(v.y), f2bf(v.z), f2bf(v.w));
  *(ushort4*)&xb[idx] = o;
}

// ---------------------------------------------------------------------------
// Kernel 2: gates = softmax(x @ Wg + bg), fp32 exact.  Wave per row.
// ---------------------------------------------------------------------------
__global__ __launch_bounds__(256) void gates_kernel(
    const float* __restrict__ text, const float* __restrict__ tech,
    const float* __restrict__ Wg, const float* __restrict__ bg,
    float* __restrict__ gates) {
  __shared__ float wgs[IND * NE];  // 32 KiB
  int t = threadIdx.x;
  for (int i = t * 4; i < IND * NE; i += 1024)
    *(float4*)&wgs[i] = *(const float4*)&Wg[i];
  __syncthreads();

  int wave = t >> 6, lane = t & 63;
  int row = blockIdx.x * 4 + wave;

  float acc[NE];
#pragma unroll
  for (int e = 0; e < NE; ++e) acc[e] = 0.f;

#pragma unroll
  for (int ii = 0; ii < 16; ++ii) {
    int i = lane * 16 + ii;
    float xv = (i < TEXT_D) ? text[(size_t)row * TEXT_D + i]
                            : tech[(size_t)row * TECH_D + (i - TEXT_D)];
    const float* wrow = &wgs[i * NE];
#pragma unroll
    for (int e = 0; e < NE; ++e) acc[e] = fmaf(xv, wrow[e], acc[e]);
  }
#pragma unroll
  for (int off = 32; off; off >>= 1)
#pragma unroll
    for (int e = 0; e < NE; ++e) acc[e] += __shfl_xor(acc[e], off);

#pragma unroll
  for (int e = 0; e < NE; ++e) acc[e] += bg[e];
  float mx = acc[0];
#pragma unroll
  for (int e = 1; e < NE; ++e) mx = fmaxf(mx, acc[e]);
  float s = 0.f;
#pragma unroll
  for (int e = 0; e < NE; ++e) { acc[e] = expf(acc[e] - mx); s += acc[e]; }
  float inv = 1.f / s;
  if (lane < NE) gates[(size_t)row * NE + lane] = acc[lane] * inv;
}

// ---------------------------------------------------------------------------
// Kernel 3: W [E][K][N] fp32 -> Wt [E][N][K] bf16   (64x64 tiles)
// ---------------------------------------------------------------------------
__global__ __launch_bounds__(256) void transpose_w(
    const float* __restrict__ W, u16* __restrict__ Wt) {
  __shared__ u16 tile[64][65];
  int bid = blockIdx.x;
  int e = bid >> 8;            // 256 tiles per 1024x1024 expert matrix
  int tb = bid & 255;
  int r0 = (tb >> 4) * 64;     // input row block (k)
  int c0 = (tb & 15) * 64;     // input col block (n)
  const float* We = W + (size_t)e * IND * OUTD;
  u16* Wte = Wt + (size_t)e * IND * OUTD;
  int t = threadIdx.x;
  int tr = t >> 4;             // 0..15
  int tc = (t & 15) * 4;       // 0..60
#pragma unroll
  for (int j = 0; j < 4; ++j) {
    int row = j * 16 + tr;
    float4 v = *(const float4*)&We[(size_t)(r0 + row) * OUTD + c0 + tc];
    tile[row][tc + 0] = f2bf(v.x);
    tile[row][tc + 1] = f2bf(v.y);
    tile[row][tc + 2] = f2bf(v.z);
    tile[row][tc + 3] = f2bf(v.w);
  }
  __syncthreads();
#pragma unroll
  for (int j = 0; j < 4; ++j) {
    int row = j * 16 + tr;     // output row (= input col n)
    ushort4 o = make_ushort4(tile[tc + 0][row], tile[tc + 1][row],
                             tile[tc + 2][row], tile[tc + 3][row]);
    *(ushort4*)&Wte[(size_t)(c0 + row) * IND + r0 + tc] = o;
  }
}

// ---------------------------------------------------------------------------
// GEMM: C[M=16384, N=1024] = A[M,1024] @ Bt[N,1024]^T   (bf16, fp32 acc)
// m97 structure: 128x128 tile, 4 waves, BK=32, LDS [kb][row][8].
// MODE 1: H = relu(C + bias) -> bf16
// MODE 2: out (+)= gates[:,e] * (C + bias)   (FIRST: write, else accumulate)
// ---------------------------------------------------------------------------
template <int MODE, bool FIRST>
__global__ __launch_bounds__(256) void gemm128(
    const u16* __restrict__ A, const u16* __restrict__ Bt,
    const float* __restrict__ bias, const float* __restrict__ gates,
    int expert, u16* __restrict__ Hout, float* __restrict__ Fout) {
  constexpr int K = 1024;
  __shared__ alignas(16) u16 As[4 * 128 * 8];  // [kb][row][8]  8 KiB
  __shared__ alignas(16) u16 Bs[4 * 128 * 8];

  int t = threadIdx.x;
  int bid = blockIdx.x;
  int nb = bid & 7, mb = bid >> 3;
  int m0 = mb * 128, n0 = nb * 128;

  int lane = t & 63;
  int w = t >> 6;
  int wr = w >> 1, wc = w & 1;       // wave -> 64x64 quadrant
  int lr = lane & 15, hi = lane >> 4;

  f32x4 acc[4][4] = {};

  // staging assignment: thread t covers LDS elems (kb0 + 2s)*1024 + (t&127)*8
  int arow = t & 127;
  int kb0 = t >> 7;  // 0 or 1
  const u16* gA = A + (size_t)(m0 + arow) * K + kb0 * 8;
  const u16* gB = Bt + (size_t)(n0 + arow) * K + kb0 * 8;
  u16* lA = &As[kb0 * 1024 + arow * 8];
  u16* lB = &Bs[kb0 * 1024 + arow * 8];

  for (int k0 = 0; k0 < K; k0 += 32) {
    gload_lds16(gA + k0, lA);
    gload_lds16(gA + k0 + 16, lA + 2048);
    gload_lds16(gB + k0, lB);
    gload_lds16(gB + k0 + 16, lB + 2048);
    __syncthreads();   // drains vmcnt -> tiles ready

    bf16x8 af[4], bf[4];
#pragma unroll
    for (int i = 0; i < 4; ++i)
      af[i] = *(const bf16x8*)&As[hi * 1024 + (wr * 64 + i * 16 + lr) * 8];
#pragma unroll
    for (int j = 0; j < 4; ++j)
      bf[j] = *(const bf16x8*)&Bs[hi * 1024 + (wc * 64 + j * 16 + lr) * 8];
#pragma unroll
    for (int i = 0; i < 4; ++i)
#pragma unroll
      for (int j = 0; j < 4; ++j)
        acc[i][j] = __builtin_amdgcn_mfma_f32_16x16x32_bf16(af[i], bf[j],
                                                            acc[i][j], 0, 0, 0);
    __syncthreads();   // all reads done before next stage overwrites
  }

  int mbase = m0 + wr * 64 + hi * 4;
  int nbase = n0 + wc * 64 + lr;
  if (MODE == 1) {
#pragma unroll
    for (int i = 0; i < 4; ++i) {
#pragma unroll
      for (int j = 0; j < 4; ++j) {
        int n = nbase + j * 16;
        float bv = bias[n];
#pragma unroll
        for (int r = 0; r < 4; ++r) {
          int m = mbase + i * 16 + r;
          float v = fmaxf(acc[i][j][r] + bv, 0.f);
          Hout[(size_t)m * OUTD + n] = f2bf(v);
        }
      }
    }
  } else {
#pragma unroll
    for (int i = 0; i < 4; ++i) {
      float g[4];
#pragma unroll
      for (int r = 0; r < 4; ++r)
        g[r] = gates[(size_t)(mbase + i * 16 + r) * NE + expert];
#pragma unroll
      for (int j = 0; j < 4; ++j) {
        int n = nbase + j * 16;
        float bv = bias[n];
#pragma unroll
        for (int r = 0; r < 4; ++r) {
          size_t oi = (size_t)(mbase + i * 16 + r) * OUTD + n;
          float v = g[r] * (acc[i][j][r] + bv);
          if (FIRST) Fout[oi] = v;
          else       Fout[oi] += v;
        }
      }
    }
  }
}

// ---------------------------------------------------------------------------
extern "C" void kernel_launch(void* const* d_in, const int* in_sizes, int n_in,
                              void* d_out, int out_size, void* d_ws, size_t ws_size,
                              hipStream_t stream) {
  (void)in_sizes; (void)n_in; (void)out_size; (void)ws_size;
  const float* text = (const float*)d_in[0];  // [NB, 768]
  const float* tech = (const float*)d_in[1];  // [NB, 256]
  const float* W1   = (const float*)d_in[2];  // [E, 1024, 1024]
  const float* b1   = (const float*)d_in[3];  // [E, 1024]
  const float* W2   = (const float*)d_in[4];  // [E, 1024, 1024]
  const float* b2   = (const float*)d_in[5];  // [E, 1024]
  const float* Wg   = (const float*)d_in[6];  // [1024, 8]
  const float* bg   = (const float*)d_in[7];  // [8]
  float* out = (float*)d_out;                 // [NB, 1024] fp32

  // workspace layout (~101.2 MB)
  char* p = (char*)d_ws;
  u16* xb  = (u16*)p;  p += (size_t)NB * IND * 2;        // 33.5 MB
  u16* W1t = (u16*)p;  p += (size_t)NE * IND * OUTD * 2; // 16.8 MB
  u16* W2t = (u16*)p;  p += (size_t)NE * OUTD * OUTD * 2;// 16.8 MB
  u16* H   = (u16*)p;  p += (size_t)NB * OUTD * 2;       // 33.5 MB
  float* gates = (float*)p;                              // 0.5 MB

  convert_x<<<dim3(NB * IND / 1024), dim3(256), 0, stream>>>(text, tech, xb);
  gates_kernel<<<dim3(NB / 4), dim3(256), 0, stream>>>(text, tech, Wg, bg, gates);
  transpose_w<<<dim3(NE * 256), dim3(256), 0, stream>>>(W1, W1t);
  transpose_w<<<dim3(NE * 256), dim3(256), 0, stream>>>(W2, W2t);

  const int gemm_grid = (NB / 128) * (OUTD / 128);  // 1024
  for (int e = 0; e < NE; ++e) {
    gemm128<1, false><<<dim3(gemm_grid), dim3(256), 0, stream>>>(
        xb, W1t + (size_t)e * IND * OUTD, b1 + (size_t)e * OUTD,
        (const float*)nullptr, e, H, (float*)nullptr);
    if (e == 0)
      gemm128<2, true><<<dim3(gemm_grid), dim3(256), 0, stream>>>(
          H, W2t + (size_t)e * OUTD * OUTD, b2 + (size_t)e * OUTD,
          gates, e, (u16*)nullptr, out);
    else
      gemm128<2, false><<<dim3(gemm_grid), dim3(256), 0, stream>>>(
          H, W2t + (size_t)e * OUTD * OUTD, b2 + (size_t)e * OUTD,
          gates, e, (u16*)nullptr, out);
  }
}

// Round 2
// 1197.329 us; speedup vs baseline: 1.2669x; 1.2669x over previous
//
#include <hip/hip_runtime.h>
#include <hip/hip_bf16.h>

// Problem constants
#define NB 16384        // batch rows
#define TEXT_D 768
#define TECH_D 256
#define IND 1024        // IN_D
#define OUTD 1024       // OUT_D
#define NE 8            // experts
#define KH 8192         // concat hidden K = NE*OUTD

typedef unsigned short u16;
typedef __bf16 bf16x8 __attribute__((ext_vector_type(8)));
typedef float f32x4 __attribute__((ext_vector_type(4)));

__device__ __forceinline__ u16 f2bf(float f) {
  union { float f; unsigned int u; } x; x.f = f;
  unsigned int u = x.u;
  return (u16)((u + 0x7FFFu + ((u >> 16) & 1u)) >> 16);
}

__device__ __forceinline__ void gload_lds16(const void* g, void* l) {
  __builtin_amdgcn_global_load_lds(
      (const __attribute__((address_space(1))) unsigned int*)g,
      (__attribute__((address_space(3))) unsigned int*)l, 16, 0, 0);
}

// ---------------------------------------------------------------------------
// Kernel 1: concat(text, tech) -> bf16 xb [NB][IND]
// ---------------------------------------------------------------------------
__global__ __launch_bounds__(256) void convert_x(
    const float* __restrict__ text, const float* __restrict__ tech,
    u16* __restrict__ xb) {
  int idx = (blockIdx.x * 256 + threadIdx.x) * 4;  // element index
  int b = idx >> 10;
  int d = idx & 1023;
  float4 v;
  if (d < TEXT_D) v = *(const float4*)&text[(size_t)b * TEXT_D + d];
  else            v = *(const float4*)&tech[(size_t)b * TECH_D + (d - TEXT_D)];
  ushort4 o = make_ushort4(f2bf(v.x), f2bf(v.y), f2bf(v.z), f2bf(v.w));
  *(ushort4*)&xb[idx] = o;
}

// ---------------------------------------------------------------------------
// Kernel 2: gates = softmax(x @ Wg + bg), fp32 exact.  Wave per row.
// ---------------------------------------------------------------------------
__global__ __launch_bounds__(256) void gates_kernel(
    const float* __restrict__ text, const float* __restrict__ tech,
    const float* __restrict__ Wg, const float* __restrict__ bg,
    float* __restrict__ gates) {
  __shared__ float wgs[IND * NE];  // 32 KiB
  int t = threadIdx.x;
  for (int i = t * 4; i < IND * NE; i += 1024)
    *(float4*)&wgs[i] = *(const float4*)&Wg[i];
  __syncthreads();

  int wave = t >> 6, lane = t & 63;
  int row = blockIdx.x * 4 + wave;

  float acc[NE];
#pragma unroll
  for (int e = 0; e < NE; ++e) acc[e] = 0.f;

#pragma unroll
  for (int ii = 0; ii < 16; ++ii) {
    int i = lane * 16 + ii;
    float xv = (i < TEXT_D) ? text[(size_t)row * TEXT_D + i]
                            : tech[(size_t)row * TECH_D + (i - TEXT_D)];
    const float* wrow = &wgs[i * NE];
#pragma unroll
    for (int e = 0; e < NE; ++e) acc[e] = fmaf(xv, wrow[e], acc[e]);
  }
#pragma unroll
  for (int off = 32; off; off >>= 1)
#pragma unroll
    for (int e = 0; e < NE; ++e) acc[e] += __shfl_xor(acc[e], off);

#pragma unroll
  for (int e = 0; e < NE; ++e) acc[e] += bg[e];
  float mx = acc[0];
#pragma unroll
  for (int e = 1; e < NE; ++e) mx = fmaxf(mx, acc[e]);
  float s = 0.f;
#pragma unroll
  for (int e = 0; e < NE; ++e) { acc[e] = expf(acc[e] - mx); s += acc[e]; }
  float inv = 1.f / s;
  if (lane < NE) gates[(size_t)row * NE + lane] = acc[lane] * inv;
}

// ---------------------------------------------------------------------------
// Kernel 3: W [E][K][N] fp32 -> Wt bf16, transposed per expert.
//   out addr = Wt + e*e_off + (n)*ostride + k
//   W1: e_off = 1<<20, ostride = 1024  -> W1t [E][N=1024][K=1024]
//   W2: e_off = 1024,  ostride = 8192  -> W2t [N=1024][E*1024 (k)]
// ---------------------------------------------------------------------------
__global__ __launch_bounds__(256) void transpose_w(
    const float* __restrict__ W, u16* __restrict__ Wt,
    int ostride, int e_off) {
  __shared__ u16 tile[64][65];
  int bid = blockIdx.x;
  int e = bid >> 8;            // 256 tiles per 1024x1024 expert matrix
  int tb = bid & 255;
  int r0 = (tb >> 4) * 64;     // input row block (k)
  int c0 = (tb & 15) * 64;     // input col block (n)
  const float* We = W + (size_t)e * IND * OUTD;
  u16* Wte = Wt + (size_t)e * e_off;
  int t = threadIdx.x;
  int tr = t >> 4;             // 0..15
  int tc = (t & 15) * 4;       // 0..60
#pragma unroll
  for (int j = 0; j < 4; ++j) {
    int row = j * 16 + tr;
    float4 v = *(const float4*)&We[(size_t)(r0 + row) * OUTD + c0 + tc];
    tile[row][tc + 0] = f2bf(v.x);
    tile[row][tc + 1] = f2bf(v.y);
    tile[row][tc + 2] = f2bf(v.z);
    tile[row][tc + 3] = f2bf(v.w);
  }
  __syncthreads();
#pragma unroll
  for (int j = 0; j < 4; ++j) {
    int row = j * 16 + tr;     // output row (= input col n)
    ushort4 o = make_ushort4(tile[tc + 0][row], tile[tc + 1][row],
                             tile[tc + 2][row], tile[tc + 3][row]);
    *(ushort4*)&Wte[(size_t)(c0 + row) * ostride + r0 + tc] = o;
  }
}

// ---------------------------------------------------------------------------
// Shared GEMM core (m97 structure): 128x128 tile, 4 waves, BK=32.
// At = A tile base (row m0, k-contiguous, row stride K)
// Bt = B tile base (row n0, k-contiguous, row stride K)
// ---------------------------------------------------------------------------
template <int K>
__device__ __forceinline__ void gemm_core(
    const u16* __restrict__ At, const u16* __restrict__ Bt,
    u16* As, u16* Bs, int t, int wr, int wc, int lr, int hi,
    f32x4 (&acc)[4][4]) {
  int arow = t & 127;
  int kb0 = t >> 7;  // 0 or 1
  const u16* gA = At + (size_t)arow * K + kb0 * 8;
  const u16* gB = Bt + (size_t)arow * K + kb0 * 8;
  u16* lA = &As[kb0 * 1024 + arow * 8];
  u16* lB = &Bs[kb0 * 1024 + arow * 8];

  for (int k0 = 0; k0 < K; k0 += 32) {
    gload_lds16(gA + k0, lA);
    gload_lds16(gA + k0 + 16, lA + 2048);
    gload_lds16(gB + k0, lB);
    gload_lds16(gB + k0 + 16, lB + 2048);
    __syncthreads();   // drains vmcnt -> tiles ready

    bf16x8 af[4], bfr[4];
#pragma unroll
    for (int i = 0; i < 4; ++i)
      af[i] = *(const bf16x8*)&As[hi * 1024 + (wr * 64 + i * 16 + lr) * 8];
#pragma unroll
    for (int j = 0; j < 4; ++j)
      bfr[j] = *(const bf16x8*)&Bs[hi * 1024 + (wc * 64 + j * 16 + lr) * 8];
#pragma unroll
    for (int i = 0; i < 4; ++i)
#pragma unroll
      for (int j = 0; j < 4; ++j)
        acc[i][j] = __builtin_amdgcn_mfma_f32_16x16x32_bf16(af[i], bfr[j],
                                                            acc[i][j], 0, 0, 0);
    __syncthreads();   // all reads done before next stage overwrites
  }
}

// ---------------------------------------------------------------------------
// GEMM1 (all experts in one dispatch):
//   Hg[m][e*1024+n] = gates[m][e] * relu(x[m]@W1_e[:,n] + b1[e][n])  (bf16)
// grid = (chM/128) * 8nb * 8e
// ---------------------------------------------------------------------------
__global__ __launch_bounds__(256) void gemm1(
    const u16* __restrict__ A, const u16* __restrict__ W1t,
    const float* __restrict__ b1, const float* __restrict__ gates,
    u16* __restrict__ Hg) {
  __shared__ alignas(16) u16 As[4096];
  __shared__ alignas(16) u16 Bs[4096];
  int t = threadIdx.x, bid = blockIdx.x;
  int nb = bid & 7, e = (bid >> 3) & 7, mb = bid >> 6;
  int m0 = mb * 128, n0 = nb * 128;
  int lane = t & 63, w = t >> 6;
  int wr = w >> 1, wc = w & 1, lr = lane & 15, hi = lane >> 4;

  f32x4 acc[4][4] = {};
  gemm_core<1024>(A + (size_t)m0 * 1024,
                  W1t + ((size_t)e << 20) + (size_t)n0 * 1024,
                  As, Bs, t, wr, wc, lr, hi, acc);

  int mbase = m0 + wr * 64 + hi * 4;
  int nbase = n0 + wc * 64 + lr;
#pragma unroll
  for (int i = 0; i < 4; ++i) {
    float g4[4];
#pragma unroll
    for (int r = 0; r < 4; ++r)
      g4[r] = gates[(size_t)(mbase + i * 16 + r) * NE + e];
#pragma unroll
    for (int j = 0; j < 4; ++j) {
      int n = nbase + j * 16;
      float bv = b1[e * OUTD + n];
#pragma unroll
      for (int r = 0; r < 4; ++r) {
        int m = mbase + i * 16 + r;
        float v = g4[r] * fmaxf(acc[i][j][r] + bv, 0.f);
        Hg[(size_t)m * KH + e * OUTD + n] = f2bf(v);
      }
    }
  }
}

// ---------------------------------------------------------------------------
// GEMM2 (single K=8192 GEMM):
//   out[m][n] = Hg[m]@W2t[n] + sum_e gates[m][e]*b2[e][n]   (fp32, write once)
// grid = (chM/128) * 8
// ---------------------------------------------------------------------------
__global__ __launch_bounds__(256) void gemm2(
    const u16* __restrict__ Hg, const u16* __restrict__ W2t,
    const float* __restrict__ b2, const float* __restrict__ gates,
    float* __restrict__ out) {
  __shared__ alignas(16) u16 As[4096];
  __shared__ alignas(16) u16 Bs[4096];
  int t = threadIdx.x, bid = blockIdx.x;
  int nb = bid & 7, mb = bid >> 3;
  int m0 = mb * 128, n0 = nb * 128;
  int lane = t & 63, w = t >> 6;
  int wr = w >> 1, wc = w & 1, lr = lane & 15, hi = lane >> 4;

  f32x4 acc[4][4] = {};
  gemm_core<KH>(Hg + (size_t)m0 * KH, W2t + (size_t)n0 * KH,
                As, Bs, t, wr, wc, lr, hi, acc);

  int mbase = m0 + wr * 64 + hi * 4;
  int nbase = n0 + wc * 64 + lr;

  // bias columns: bcol[j][e] = b2[e][nbase + j*16]
  float bcol[4][NE];
#pragma unroll
  for (int j = 0; j < 4; ++j)
#pragma unroll
    for (int e = 0; e < NE; ++e)
      bcol[j][e] = b2[e * OUTD + nbase + j * 16];

#pragma unroll
  for (int i = 0; i < 4; ++i) {
#pragma unroll
    for (int r = 0; r < 4; ++r) {
      int m = mbase + i * 16 + r;
      float4 ga = *(const float4*)&gates[(size_t)m * NE];
      float4 gb = *(const float4*)&gates[(size_t)m * NE + 4];
#pragma unroll
      for (int j = 0; j < 4; ++j) {
        float bias = ga.x * bcol[j][0] + ga.y * bcol[j][1] +
                     ga.z * bcol[j][2] + ga.w * bcol[j][3] +
                     gb.x * bcol[j][4] + gb.y * bcol[j][5] +
                     gb.z * bcol[j][6] + gb.w * bcol[j][7];
        out[(size_t)m * OUTD + nbase + j * 16] = acc[i][j][r] + bias;
      }
    }
  }
}

// ---------------------------------------------------------------------------
extern "C" void kernel_launch(void* const* d_in, const int* in_sizes, int n_in,
                              void* d_out, int out_size, void* d_ws, size_t ws_size,
                              hipStream_t stream) {
  (void)in_sizes; (void)n_in; (void)out_size;
  const float* text = (const float*)d_in[0];  // [NB, 768]
  const float* tech = (const float*)d_in[1];  // [NB, 256]
  const float* W1   = (const float*)d_in[2];  // [E, 1024, 1024]
  const float* b1   = (const float*)d_in[3];  // [E, 1024]
  const float* W2   = (const float*)d_in[4];  // [E, 1024, 1024]
  const float* b2   = (const float*)d_in[5];  // [E, 1024]
  const float* Wg   = (const float*)d_in[6];  // [1024, 8]
  const float* bg   = (const float*)d_in[7];  // [8]
  float* out = (float*)d_out;                 // [NB, 1024] fp32

  // workspace layout: fixed part = 67.6 MB, Hg chunk variable
  char* p = (char*)d_ws;
  u16* xb  = (u16*)p;  p += (size_t)NB * IND * 2;        // 33.5 MB
  u16* W1t = (u16*)p;  p += (size_t)NE * IND * OUTD * 2; // 16.8 MB
  u16* W2t = (u16*)p;  p += (size_t)NE * OUTD * OUTD * 2;// 16.8 MB
  float* gates = (float*)p; p += (size_t)NB * NE * 4;    // 0.5 MB
  u16* Hg  = (u16*)p;                                    // CH * 16 KB

  size_t fixed = (size_t)(p - (char*)d_ws);
  int CH = 2048;  // proven-safe footprint (101 MB total)
  if      (ws_size >= fixed + (size_t)16384 * KH * 2) CH = 16384;
  else if (ws_size >= fixed + (size_t)8192  * KH * 2) CH = 8192;
  else if (ws_size >= fixed + (size_t)4096  * KH * 2) CH = 4096;

  convert_x<<<dim3(NB * IND / 1024), dim3(256), 0, stream>>>(text, tech, xb);
  gates_kernel<<<dim3(NB / 4), dim3(256), 0, stream>>>(text, tech, Wg, bg, gates);
  transpose_w<<<dim3(NE * 256), dim3(256), 0, stream>>>(W1, W1t, 1024, IND * OUTD);
  transpose_w<<<dim3(NE * 256), dim3(256), 0, stream>>>(W2, W2t, KH, OUTD);

  for (int c0 = 0; c0 < NB; c0 += CH) {
    gemm1<<<dim3((CH / 128) * 64), dim3(256), 0, stream>>>(
        xb + (size_t)c0 * IND, W1t, b1, gates + (size_t)c0 * NE, Hg);
    gemm2<<<dim3((CH / 128) * 8), dim3(256), 0, stream>>>(
        Hg, W2t, b2, gates + (size_t)c0 * NE, out + (size_t)c0 * OUTD);
  }
}

// Round 3
// 843.502 us; speedup vs baseline: 1.7983x; 1.4195x over previous
//
#include <hip/hip_runtime.h>
#include <hip/hip_bf16.h>

// Problem constants
#define NB 16384        // batch rows
#define TEXT_D 768
#define TECH_D 256
#define IND 1024        // IN_D
#define OUTD 1024       // OUT_D
#define NE 8            // experts
#define KH 8192         // concat hidden K = NE*OUTD

typedef unsigned short u16;
typedef __bf16 bf16x8 __attribute__((ext_vector_type(8)));
typedef float f32x4 __attribute__((ext_vector_type(4)));

__device__ __forceinline__ u16 f2bf(float f) {
  union { float f; unsigned int u; } x; x.f = f;
  unsigned int u = x.u;
  return (u16)((u + 0x7FFFu + ((u >> 16) & 1u)) >> 16);
}

__device__ __forceinline__ void gload_lds16(const void* g, void* l) {
  __builtin_amdgcn_global_load_lds(
      (const __attribute__((address_space(1))) unsigned int*)g,
      (__attribute__((address_space(3))) unsigned int*)l, 16, 0, 0);
}

// ---------------------------------------------------------------------------
// Kernel 1: concat(text, tech) -> bf16 xb [NB][IND]
// ---------------------------------------------------------------------------
__global__ __launch_bounds__(256) void convert_x(
    const float* __restrict__ text, const float* __restrict__ tech,
    u16* __restrict__ xb) {
  int idx = (blockIdx.x * 256 + threadIdx.x) * 4;
  int b = idx >> 10;
  int d = idx & 1023;
  float4 v;
  if (d < TEXT_D) v = *(const float4*)&text[(size_t)b * TEXT_D + d];
  else            v = *(const float4*)&tech[(size_t)b * TECH_D + (d - TEXT_D)];
  ushort4 o = make_ushort4(f2bf(v.x), f2bf(v.y), f2bf(v.z), f2bf(v.w));
  *(ushort4*)&xb[idx] = o;
}

// ---------------------------------------------------------------------------
// Kernel 2: gates = softmax(x @ Wg + bg), fp32 exact.  Wave per row.
// ---------------------------------------------------------------------------
__global__ __launch_bounds__(256) void gates_kernel(
    const float* __restrict__ text, const float* __restrict__ tech,
    const float* __restrict__ Wg, const float* __restrict__ bg,
    float* __restrict__ gates) {
  __shared__ float wgs[IND * NE];  // 32 KiB
  int t = threadIdx.x;
  for (int i = t * 4; i < IND * NE; i += 1024)
    *(float4*)&wgs[i] = *(const float4*)&Wg[i];
  __syncthreads();

  int wave = t >> 6, lane = t & 63;
  int row = blockIdx.x * 4 + wave;

  float acc[NE];
#pragma unroll
  for (int e = 0; e < NE; ++e) acc[e] = 0.f;

#pragma unroll
  for (int ii = 0; ii < 16; ++ii) {
    int i = lane * 16 + ii;
    float xv = (i < TEXT_D) ? text[(size_t)row * TEXT_D + i]
                            : tech[(size_t)row * TECH_D + (i - TEXT_D)];
    const float* wrow = &wgs[i * NE];
#pragma unroll
    for (int e = 0; e < NE; ++e) acc[e] = fmaf(xv, wrow[e], acc[e]);
  }
#pragma unroll
  for (int off = 32; off; off >>= 1)
#pragma unroll
    for (int e = 0; e < NE; ++e) acc[e] += __shfl_xor(acc[e], off);

#pragma unroll
  for (int e = 0; e < NE; ++e) acc[e] += bg[e];
  float mx = acc[0];
#pragma unroll
  for (int e = 1; e < NE; ++e) mx = fmaxf(mx, acc[e]);
  float s = 0.f;
#pragma unroll
  for (int e = 0; e < NE; ++e) { acc[e] = expf(acc[e] - mx); s += acc[e]; }
  float inv = 1.f / s;
  if (lane < NE) gates[(size_t)row * NE + lane] = acc[lane] * inv;
}

// ---------------------------------------------------------------------------
// Kernel 3 (fused): W1 and W2 fp32 -> bf16 transposed.
//   blocks [0,2048):   W1 -> W1t [E][N=1024][K=1024]
//   blocks [2048,4096): W2 -> W2t [N=1024][KH=8192]
// ---------------------------------------------------------------------------
__global__ __launch_bounds__(256) void transpose_w12(
    const float* __restrict__ W1, const float* __restrict__ W2,
    u16* __restrict__ W1t, u16* __restrict__ W2t) {
  __shared__ u16 tile[64][65];
  int bid = blockIdx.x;
  int half = bid >> 11;
  int b2 = bid & 2047;
  const float* W; u16* Wt; int ostride; size_t e_off;
  if (half == 0) { W = W1; Wt = W1t; ostride = 1024; e_off = (size_t)IND * OUTD; }
  else           { W = W2; Wt = W2t; ostride = KH;   e_off = OUTD; }
  int e = b2 >> 8;
  int tb = b2 & 255;
  int r0 = (tb >> 4) * 64;     // input row block (k)
  int c0 = (tb & 15) * 64;     // input col block (n)
  const float* We = W + (size_t)e * IND * OUTD;
  u16* Wte = Wt + (size_t)e * e_off;
  int t = threadIdx.x;
  int tr = t >> 4;
  int tc = (t & 15) * 4;
#pragma unroll
  for (int j = 0; j < 4; ++j) {
    int row = j * 16 + tr;
    float4 v = *(const float4*)&We[(size_t)(r0 + row) * OUTD + c0 + tc];
    tile[row][tc + 0] = f2bf(v.x);
    tile[row][tc + 1] = f2bf(v.y);
    tile[row][tc + 2] = f2bf(v.z);
    tile[row][tc + 3] = f2bf(v.w);
  }
  __syncthreads();
#pragma unroll
  for (int j = 0; j < 4; ++j) {
    int row = j * 16 + tr;
    ushort4 o = make_ushort4(tile[tc + 0][row], tile[tc + 1][row],
                             tile[tc + 2][row], tile[tc + 3][row]);
    *(ushort4*)&Wte[(size_t)(c0 + row) * ostride + r0 + tc] = o;
  }
}

// ---------------------------------------------------------------------------
// 256x256 8-phase GEMM core (BK=64, 8 waves 2x4, 128 KiB LDS, T2+T3+T4+T5).
// LDS per buf: A [256 rows][64 cols] bf16 (32 KB) + B same (32 KB); x2 bufs.
// Swizzle: LDS[r][c2] holds G[r][c2 ^ ((r&7)<<4)] (byte cols, 16B units);
// staging writes linear (global_load_lds), source pre-swizzled; reads XOR.
// Staging slots per K-tile (each 16 KB = 2 loads/thread):
//   0: A rows {0-63,128-191}  1: B rows {r:(r&63)<32}
//   2: B rows {r:(r&63)>=32}  3: A rows {64-127,192-255}
// Phase p issues slot p of tile T+1; vmcnt(4) keeps 3 half-tiles in flight.
// ---------------------------------------------------------------------------
#define BAR() asm volatile("s_barrier" ::: "memory")
#define VM4() asm volatile("s_waitcnt vmcnt(4)" ::: "memory")

template <int SLOT, int K>
__device__ __forceinline__ void stage_slot(
    const u16* __restrict__ pA, const u16* __restrict__ pB, char* sb, int k0,
    int ch0, int rsub, int koff, int lbyte) {
#pragma unroll
  for (int j = 0; j < 2; ++j) {
    int ch = ch0 + j;
    int r;
    if constexpr (SLOT == 0)      r = (ch >> 3) * 128 + (ch & 7) * 8 + rsub;
    else if constexpr (SLOT == 3) r = 64 + (ch >> 3) * 128 + (ch & 7) * 8 + rsub;
    else if constexpr (SLOT == 1) r = (ch >> 2) * 64 + (ch & 3) * 8 + rsub;
    else                          r = (ch >> 2) * 64 + 32 + (ch & 3) * 8 + rsub;
    const u16* g = (SLOT == 0 || SLOT == 3) ? pA : pB;
    char* lb = sb + ((SLOT == 0 || SLOT == 3) ? 0 : 32768) + r * 128 + lbyte;
    gload_lds16(g + (size_t)r * K + k0 + koff, lb);
  }
}

template <int QH>
__device__ __forceinline__ void load_a(const char* rb, int wr, int lr, int hi,
                                       int swr, bf16x8 (&a)[4][2]) {
#pragma unroll
  for (int i = 0; i < 4; ++i)
#pragma unroll
    for (int ks = 0; ks < 2; ++ks)
      a[i][ks] = *(const bf16x8*)(rb + (wr * 128 + QH * 64 + i * 16 + lr) * 128
                                  + ((ks * 64 + hi * 16) ^ swr));
}

template <int NH>
__device__ __forceinline__ void load_b(const char* rb, int wc, int lr, int hi,
                                       int swr, bf16x8 (&b)[2][2]) {
#pragma unroll
  for (int q = 0; q < 2; ++q)
#pragma unroll
    for (int ks = 0; ks < 2; ++ks)
      b[q][ks] = *(const bf16x8*)(rb + 32768 +
                                  (wc * 64 + (NH * 2 + q) * 16 + lr) * 128
                                  + ((ks * 64 + hi * 16) ^ swr));
}

template <int MH, int NH>
__device__ __forceinline__ void mfma_quad(const bf16x8 (&a)[4][2],
                                          const bf16x8 (&b)[2][2],
                                          f32x4 (&acc)[8][4]) {
  __builtin_amdgcn_s_setprio(1);
#pragma unroll
  for (int i = 0; i < 4; ++i)
#pragma unroll
    for (int q = 0; q < 2; ++q) {
      acc[MH*4+i][NH*2+q] = __builtin_amdgcn_mfma_f32_16x16x32_bf16(
          a[i][0], b[q][0], acc[MH*4+i][NH*2+q], 0, 0, 0);
      acc[MH*4+i][NH*2+q] = __builtin_amdgcn_mfma_f32_16x16x32_bf16(
          a[i][1], b[q][1], acc[MH*4+i][NH*2+q], 0, 0, 0);
    }
  __builtin_amdgcn_s_setprio(0);
}

template <int RB, int K>
__device__ __forceinline__ void ktile(
    const u16* __restrict__ pA, const u16* __restrict__ pB, char* lds, int k0s,
    int ch0, int rsub, int koff, int lbyte,
    int wr, int wc, int lr, int hi, int swr,
    bf16x8 (&a)[4][2], bf16x8 (&b0)[2][2], bf16x8 (&b1)[2][2],
    f32x4 (&acc)[8][4]) {
  const char* rb = lds + RB * 65536;
  char* sb = lds + (RB ^ 1) * 65536;
  // ph1 (mh0,nh0)
  load_a<0>(rb, wr, lr, hi, swr, a);
  load_b<0>(rb, wc, lr, hi, swr, b0);
  stage_slot<0, K>(pA, pB, sb, k0s, ch0, rsub, koff, lbyte);
  VM4(); BAR();
  mfma_quad<0, 0>(a, b0, acc);
  BAR();
  // ph2 (mh0,nh1)
  load_b<1>(rb, wc, lr, hi, swr, b1);
  stage_slot<1, K>(pA, pB, sb, k0s, ch0, rsub, koff, lbyte);
  VM4(); BAR();
  mfma_quad<0, 1>(a, b1, acc);
  BAR();
  // ph3 (mh1,nh0)
  load_a<1>(rb, wr, lr, hi, swr, a);
  stage_slot<2, K>(pA, pB, sb, k0s, ch0, rsub, koff, lbyte);
  VM4(); BAR();
  mfma_quad<1, 0>(a, b0, acc);
  BAR();
  // ph4 (mh1,nh1)
  stage_slot<3, K>(pA, pB, sb, k0s, ch0, rsub, koff, lbyte);
  VM4(); BAR();
  mfma_quad<1, 1>(a, b1, acc);
  BAR();
}

template <int K>
__device__ __forceinline__ void core256(const u16* __restrict__ pA,
                                        const u16* __restrict__ pB,
                                        char* lds, int t, f32x4 (&acc)[8][4]) {
  constexpr int KT = K / 64;
  const int l = t & 63;
  const int w = t >> 6;
  const int wr = w >> 2, wc = w & 3;
  const int lr = l & 15, hi = l >> 4;
  const int rsub = l >> 3;
  const int koff = ((l & 7) ^ rsub) << 3;  // swizzled source col (elements)
  const int lbyte = (l & 7) * 16;
  const int ch0 = w * 2;
  const int swr = (lr & 7) << 4;           // read-side swizzle (bytes)

  bf16x8 a[4][2], b0[2][2], b1[2][2];

  // prologue: stage tile 0 -> buf0; wait slots 0,1
  stage_slot<0, K>(pA, pB, lds, 0, ch0, rsub, koff, lbyte);
  stage_slot<1, K>(pA, pB, lds, 0, ch0, rsub, koff, lbyte);
  stage_slot<2, K>(pA, pB, lds, 0, ch0, rsub, koff, lbyte);
  stage_slot<3, K>(pA, pB, lds, 0, ch0, rsub, koff, lbyte);
  VM4(); BAR();

  for (int T = 0; T < KT; T += 2) {
    int k1 = (T + 1) * 64;
    int k2 = (T + 2 < KT) ? (T + 2) * 64 : 0;  // clamped redundant stage at end
    ktile<0, K>(pA, pB, lds, k1, ch0, rsub, koff, lbyte,
                wr, wc, lr, hi, swr, a, b0, b1, acc);
    ktile<1, K>(pA, pB, lds, k2, ch0, rsub, koff, lbyte,
                wr, wc, lr, hi, swr, a, b0, b1, acc);
  }
  asm volatile("s_waitcnt vmcnt(0)" ::: "memory");  // drain before LDS dealloc
}

// ---------------------------------------------------------------------------
// GEMM1: Hg[m][e*1024+n] = gates[m][e]*relu(x@W1_e + b1_e)  (bf16)
// grid = (CH/256) * 4 * 8
// ---------------------------------------------------------------------------
__global__ __launch_bounds__(512, 2) void gemm1(
    const u16* __restrict__ xb, const u16* __restrict__ W1t,
    const float* __restrict__ b1, const float* __restrict__ gates,
    u16* __restrict__ Hg) {
  __shared__ char lds[131072];
  int t = threadIdx.x;
  int nwg = gridDim.x, cpx = nwg >> 3, bid = blockIdx.x;
  int swz = (bid & 7) * cpx + (bid >> 3);  // bijective XCD swizzle (nwg%8==0)
  int nb = swz & 3, e = (swz >> 2) & 7, mb = swz >> 5;

  f32x4 acc[8][4] = {};
  core256<1024>(xb + (size_t)mb * 256 * 1024,
                W1t + ((size_t)e << 20) + (size_t)nb * 256 * 1024,
                lds, t, acc);

  int l = t & 63, w = t >> 6, wr = w >> 2, wc = w & 3, lr = l & 15, hi = l >> 4;
  int m0 = mb * 256 + wr * 128 + hi * 4;
  int n0 = nb * 256 + wc * 64 + lr;
  const float* b1e = b1 + e * OUTD;
#pragma unroll
  for (int m = 0; m < 8; ++m) {
#pragma unroll
    for (int r = 0; r < 4; ++r) {
      int row = m0 + m * 16 + r;
      float g = gates[(size_t)row * NE + e];
#pragma unroll
      for (int nn = 0; nn < 4; ++nn) {
        int n = n0 + nn * 16;
        float v = g * fmaxf(acc[m][nn][r] + b1e[n], 0.f);
        Hg[(size_t)row * KH + e * OUTD + n] = f2bf(v);
      }
    }
  }
}

// ---------------------------------------------------------------------------
// GEMM2: out[m][n] = Hg[m]@W2t[n] + sum_e gates[m][e]*b2[e][n]  (fp32)
// grid = (CH/256) * 4
// ---------------------------------------------------------------------------
__global__ __launch_bounds__(512, 2) void gemm2(
    const u16* __restrict__ Hg, const u16* __restrict__ W2t,
    const float* __restrict__ b2, const float* __restrict__ gates,
    float* __restrict__ out) {
  __shared__ char lds[131072];
  int t = threadIdx.x;
  int nwg = gridDim.x, cpx = nwg >> 3, bid = blockIdx.x;
  int swz = (bid & 7) * cpx + (bid >> 3);
  int nb = swz & 3, mb = swz >> 2;

  f32x4 acc[8][4] = {};
  core256<KH>(Hg + (size_t)mb * 256 * KH, W2t + (size_t)nb * 256 * KH,
              lds, t, acc);

  int l = t & 63, w = t >> 6, wr = w >> 2, wc = w & 3, lr = l & 15, hi = l >> 4;
  int m0 = mb * 256 + wr * 128 + hi * 4;
  int n0 = nb * 256 + wc * 64 + lr;

  float bcol[4][NE];
#pragma unroll
  for (int nn = 0; nn < 4; ++nn)
#pragma unroll
    for (int e = 0; e < NE; ++e)
      bcol[nn][e] = b2[e * OUTD + n0 + nn * 16];

#pragma unroll
  for (int m = 0; m < 8; ++m) {
#pragma unroll
    for (int r = 0; r < 4; ++r) {
      int row = m0 + m * 16 + r;
      float4 ga = *(const float4*)&gates[(size_t)row * NE];
      float4 gb = *(const float4*)&gates[(size_t)row * NE + 4];
#pragma unroll
      for (int nn = 0; nn < 4; ++nn) {
        float bias = ga.x * bcol[nn][0] + ga.y * bcol[nn][1] +
                     ga.z * bcol[nn][2] + ga.w * bcol[nn][3] +
                     gb.x * bcol[nn][4] + gb.y * bcol[nn][5] +
                     gb.z * bcol[nn][6] + gb.w * bcol[nn][7];
        out[(size_t)row * OUTD + n0 + nn * 16] = acc[m][nn][r] + bias;
      }
    }
  }
}

// ---------------------------------------------------------------------------
extern "C" void kernel_launch(void* const* d_in, const int* in_sizes, int n_in,
                              void* d_out, int out_size, void* d_ws, size_t ws_size,
                              hipStream_t stream) {
  (void)in_sizes; (void)n_in; (void)out_size;
  const float* text = (const float*)d_in[0];
  const float* tech = (const float*)d_in[1];
  const float* W1   = (const float*)d_in[2];
  const float* b1   = (const float*)d_in[3];
  const float* W2   = (const float*)d_in[4];
  const float* b2   = (const float*)d_in[5];
  const float* Wg   = (const float*)d_in[6];
  const float* bg   = (const float*)d_in[7];
  float* out = (float*)d_out;

  // workspace: fixed 67.6 MB + Hg chunk
  char* p = (char*)d_ws;
  u16* xb  = (u16*)p;  p += (size_t)NB * IND * 2;
  u16* W1t = (u16*)p;  p += (size_t)NE * IND * OUTD * 2;
  u16* W2t = (u16*)p;  p += (size_t)NE * OUTD * OUTD * 2;
  float* gates = (float*)p; p += (size_t)NB * NE * 4;
  u16* Hg  = (u16*)p;

  size_t fixed = (size_t)(p - (char*)d_ws);
  int CH = 2048;
  if      (ws_size >= fixed + (size_t)16384 * KH * 2) CH = 16384;
  else if (ws_size >= fixed + (size_t)8192  * KH * 2) CH = 8192;
  else if (ws_size >= fixed + (size_t)4096  * KH * 2) CH = 4096;

  convert_x<<<dim3(NB * IND / 1024), dim3(256), 0, stream>>>(text, tech, xb);
  gates_kernel<<<dim3(NB / 4), dim3(256), 0, stream>>>(text, tech, Wg, bg, gates);
  transpose_w12<<<dim3(4096), dim3(256), 0, stream>>>(W1, W2, W1t, W2t);

  for (int c0 = 0; c0 < NB; c0 += CH) {
    gemm1<<<dim3((CH / 256) * 32), dim3(512), 0, stream>>>(
        xb + (size_t)c0 * IND, W1t, b1, gates + (size_t)c0 * NE, Hg);
    gemm2<<<dim3((CH / 256) * 4), dim3(512), 0, stream>>>(
        Hg, W2t, b2, gates + (size_t)c0 * NE, out + (size_t)c0 * OUTD);
  }
}

// Round 4
// 612.864 us; speedup vs baseline: 2.4750x; 1.3763x over previous
//
#include <hip/hip_runtime.h>
#include <hip/hip_bf16.h>

// Problem constants
#define NB 16384        // batch rows
#define TEXT_D 768
#define TECH_D 256
#define IND 1024        // IN_D
#define OUTD 1024       // OUT_D
#define NE 8            // experts
#define KH2 4096        // half-hidden K = 4 experts * 1024

typedef unsigned short u16;
typedef __bf16 bf16x8 __attribute__((ext_vector_type(8)));
typedef float f32x4 __attribute__((ext_vector_type(4)));

__device__ __forceinline__ u16 f2bf(float f) {
  union { float f; unsigned int u; } x; x.f = f;
  unsigned int u = x.u;
  return (u16)((u + 0x7FFFu + ((u >> 16) & 1u)) >> 16);
}

__device__ __forceinline__ void gload_lds16(const void* g, void* l) {
  __builtin_amdgcn_global_load_lds(
      (const __attribute__((address_space(1))) unsigned int*)g,
      (__attribute__((address_space(3))) unsigned int*)l, 16, 0, 0);
}

// ---------------------------------------------------------------------------
// Fused: concat->bf16 xb  AND  gates = softmax(x@Wg + bg).
// Block = 256 threads = 4 waves; wave per row. Wg (32KB) read via L1.
// ---------------------------------------------------------------------------
__global__ __launch_bounds__(256) void convert_gates(
    const float* __restrict__ text, const float* __restrict__ tech,
    const float* __restrict__ Wg, const float* __restrict__ bg,
    u16* __restrict__ xb, float* __restrict__ gates) {
  int t = threadIdx.x;
  int wave = t >> 6, lane = t & 63;
  int row = blockIdx.x * 4 + wave;

  float acc[NE];
#pragma unroll
  for (int e = 0; e < NE; ++e) acc[e] = 0.f;

#pragma unroll
  for (int j = 0; j < 4; ++j) {
    int col = j * 256 + lane * 4;
    float4 v = (j < 3) ? *(const float4*)&text[(size_t)row * TEXT_D + col]
                       : *(const float4*)&tech[(size_t)row * TECH_D + lane * 4];
    ushort4 o = make_ushort4(f2bf(v.x), f2bf(v.y), f2bf(v.z), f2bf(v.w));
    *(ushort4*)&xb[(size_t)row * IND + col] = o;
    const float* wp = &Wg[(size_t)col * NE];
    float xv[4] = {v.x, v.y, v.z, v.w};
#pragma unroll
    for (int i = 0; i < 4; ++i) {
      float4 w0 = *(const float4*)&wp[i * NE];
      float4 w1 = *(const float4*)&wp[i * NE + 4];
      acc[0] = fmaf(xv[i], w0.x, acc[0]);
      acc[1] = fmaf(xv[i], w0.y, acc[1]);
      acc[2] = fmaf(xv[i], w0.z, acc[2]);
      acc[3] = fmaf(xv[i], w0.w, acc[3]);
      acc[4] = fmaf(xv[i], w1.x, acc[4]);
      acc[5] = fmaf(xv[i], w1.y, acc[5]);
      acc[6] = fmaf(xv[i], w1.z, acc[6]);
      acc[7] = fmaf(xv[i], w1.w, acc[7]);
    }
  }
#pragma unroll
  for (int off = 32; off; off >>= 1)
#pragma unroll
    for (int e = 0; e < NE; ++e) acc[e] += __shfl_xor(acc[e], off);

#pragma unroll
  for (int e = 0; e < NE; ++e) acc[e] += bg[e];
  float mx = acc[0];
#pragma unroll
  for (int e = 1; e < NE; ++e) mx = fmaxf(mx, acc[e]);
  float s = 0.f;
#pragma unroll
  for (int e = 0; e < NE; ++e) { acc[e] = expf(acc[e] - mx); s += acc[e]; }
  float inv = 1.f / s;
  if (lane < NE) gates[(size_t)row * NE + lane] = acc[lane] * inv;
}

// ---------------------------------------------------------------------------
// Transpose fp32 W -> bf16, both weights in one dispatch.
//   blocks [0,2048):   W1[e][k][n] -> W1t[e][n*1024 + k]
//   blocks [2048,4096): W2[e][k][n] -> W2t[e>>2][n*4096 + (e&3)*1024 + k]
// ---------------------------------------------------------------------------
__global__ __launch_bounds__(256) void transpose_w12(
    const float* __restrict__ W1, const float* __restrict__ W2,
    u16* __restrict__ W1t, u16* __restrict__ W2t) {
  __shared__ u16 tile[64][65];
  int bid = blockIdx.x;
  int half = bid >> 11;
  int b2 = bid & 2047;
  int e = b2 >> 8;
  int tb = b2 & 255;
  int r0 = (tb >> 4) * 64;     // input row block (k)
  int c0 = (tb & 15) * 64;     // input col block (n)
  const float* We; u16* Wte; int ostride;
  if (half == 0) {
    We = W1 + (size_t)e * IND * OUTD;
    Wte = W1t + ((size_t)e << 20);
    ostride = 1024;
  } else {
    We = W2 + (size_t)e * IND * OUTD;
    Wte = W2t + ((size_t)(e >> 2) << 22) + (size_t)(e & 3) * 1024;
    ostride = KH2;
  }
  int t = threadIdx.x;
  int tr = t >> 4;
  int tc = (t & 15) * 4;
#pragma unroll
  for (int j = 0; j < 4; ++j) {
    int row = j * 16 + tr;
    float4 v = *(const float4*)&We[(size_t)(r0 + row) * OUTD + c0 + tc];
    tile[row][tc + 0] = f2bf(v.x);
    tile[row][tc + 1] = f2bf(v.y);
    tile[row][tc + 2] = f2bf(v.z);
    tile[row][tc + 3] = f2bf(v.w);
  }
  __syncthreads();
#pragma unroll
  for (int j = 0; j < 4; ++j) {
    int row = j * 16 + tr;     // output row (= input col n)
    ushort4 o = make_ushort4(tile[tc + 0][row], tile[tc + 1][row],
                             tile[tc + 2][row], tile[tc + 3][row]);
    *(ushort4*)&Wte[(size_t)(c0 + row) * ostride + r0 + tc] = o;
  }
}

// ---------------------------------------------------------------------------
// 256x256 8-phase GEMM core (BK=64, 8 waves 2x4, 128 KiB LDS).
// LDS per buf: A [256][64] bf16 (32 KB) + B same; x2 bufs. XOR-swizzled
// both-sides (linear global_load_lds dest, pre-swizzled source, XOR reads).
// Slots/K-tile: 0:A rows{0-63,128-191} 1:B lo-half 2:B hi-half 3:A{64-127,...}
// Phase p issues slot p of tile T+1; VM4 forces slot completion 2 phases
// after issue, one phase before its ds_read. LAST tile: drain ladder.
// ---------------------------------------------------------------------------
#define BAR() asm volatile("s_barrier" ::: "memory")
#define VM4() asm volatile("s_waitcnt vmcnt(4)" ::: "memory")

template <int SLOT, int K>
__device__ __forceinline__ void stage_slot(
    const u16* __restrict__ pA, const u16* __restrict__ pB, char* sb, int k0,
    int ch0, int rsub, int koff, int lbyte) {
#pragma unroll
  for (int j = 0; j < 2; ++j) {
    int ch = ch0 + j;
    int r;
    if constexpr (SLOT == 0)      r = (ch >> 3) * 128 + (ch & 7) * 8 + rsub;
    else if constexpr (SLOT == 3) r = 64 + (ch >> 3) * 128 + (ch & 7) * 8 + rsub;
    else if constexpr (SLOT == 1) r = (ch >> 2) * 64 + (ch & 3) * 8 + rsub;
    else                          r = (ch >> 2) * 64 + 32 + (ch & 3) * 8 + rsub;
    const u16* g = (SLOT == 0 || SLOT == 3) ? pA : pB;
    char* lb = sb + ((SLOT == 0 || SLOT == 3) ? 0 : 32768) + r * 128 + lbyte;
    gload_lds16(g + (size_t)r * K + k0 + koff, lb);
  }
}

template <int QH>
__device__ __forceinline__ void load_a(const char* rb, int wr, int lr, int hi,
                                       int swr, bf16x8 (&a)[4][2]) {
#pragma unroll
  for (int i = 0; i < 4; ++i)
#pragma unroll
    for (int ks = 0; ks < 2; ++ks)
      a[i][ks] = *(const bf16x8*)(rb + (wr * 128 + QH * 64 + i * 16 + lr) * 128
                                  + ((ks * 64 + hi * 16) ^ swr));
}

template <int NH>
__device__ __forceinline__ void load_b(const char* rb, int wc, int lr, int hi,
                                       int swr, bf16x8 (&b)[2][2]) {
#pragma unroll
  for (int q = 0; q < 2; ++q)
#pragma unroll
    for (int ks = 0; ks < 2; ++ks)
      b[q][ks] = *(const bf16x8*)(rb + 32768 +
                                  (wc * 64 + (NH * 2 + q) * 16 + lr) * 128
                                  + ((ks * 64 + hi * 16) ^ swr));
}

template <int MH, int NH>
__device__ __forceinline__ void mfma_quad(const bf16x8 (&a)[4][2],
                                          const bf16x8 (&b)[2][2],
                                          f32x4 (&acc)[8][4]) {
  __builtin_amdgcn_s_setprio(1);
#pragma unroll
  for (int i = 0; i < 4; ++i)
#pragma unroll
    for (int q = 0; q < 2; ++q) {
      acc[MH*4+i][NH*2+q] = __builtin_amdgcn_mfma_f32_16x16x32_bf16(
          a[i][0], b[q][0], acc[MH*4+i][NH*2+q], 0, 0, 0);
      acc[MH*4+i][NH*2+q] = __builtin_amdgcn_mfma_f32_16x16x32_bf16(
          a[i][1], b[q][1], acc[MH*4+i][NH*2+q], 0, 0, 0);
    }
  __builtin_amdgcn_s_setprio(0);
}

template <int RB, int K, bool LAST>
__device__ __forceinline__ void ktile(
    const u16* __restrict__ pA, const u16* __restrict__ pB, char* lds, int k0s,
    int ch0, int rsub, int koff, int lbyte,
    int wr, int wc, int lr, int hi, int swr,
    bf16x8 (&a)[4][2], bf16x8 (&b0)[2][2], bf16x8 (&b1)[2][2],
    f32x4 (&acc)[8][4]) {
  const char* rb = lds + RB * 65536;
  char* sb = lds + (RB ^ 1) * 65536;
  // ph1 (mh0,nh0)
  load_a<0>(rb, wr, lr, hi, swr, a);
  load_b<0>(rb, wc, lr, hi, swr, b0);
  if constexpr (!LAST) { stage_slot<0, K>(pA, pB, sb, k0s, ch0, rsub, koff, lbyte); VM4(); }
  else                 { asm volatile("s_waitcnt vmcnt(2)" ::: "memory"); }
  BAR();
  mfma_quad<0, 0>(a, b0, acc);
  BAR();
  // ph2 (mh0,nh1)
  load_b<1>(rb, wc, lr, hi, swr, b1);
  if constexpr (!LAST) { stage_slot<1, K>(pA, pB, sb, k0s, ch0, rsub, koff, lbyte); VM4(); }
  else                 { asm volatile("s_waitcnt vmcnt(0)" ::: "memory"); }
  BAR();
  mfma_quad<0, 1>(a, b1, acc);
  BAR();
  // ph3 (mh1,nh0)
  load_a<1>(rb, wr, lr, hi, swr, a);
  if constexpr (!LAST) { stage_slot<2, K>(pA, pB, sb, k0s, ch0, rsub, koff, lbyte); VM4(); }
  BAR();
  mfma_quad<1, 0>(a, b0, acc);
  BAR();
  // ph4 (mh1,nh1)
  if constexpr (!LAST) { stage_slot<3, K>(pA, pB, sb, k0s, ch0, rsub, koff, lbyte); VM4(); }
  BAR();
  mfma_quad<1, 1>(a, b1, acc);
  BAR();
}

template <int K>
__device__ __forceinline__ void core256(const u16* __restrict__ pA,
                                        const u16* __restrict__ pB,
                                        char* lds, int t, f32x4 (&acc)[8][4]) {
  constexpr int KT = K / 64;
  const int l = t & 63;
  const int w = t >> 6;
  const int wr = w >> 2, wc = w & 3;
  const int lr = l & 15, hi = l >> 4;
  const int rsub = l >> 3;
  const int koff = ((l & 7) ^ rsub) << 3;  // pre-swizzled source col (elems)
  const int lbyte = (l & 7) * 16;
  const int ch0 = w * 2;
  const int swr = (lr & 7) << 4;           // read-side swizzle (bytes)

  bf16x8 a[4][2], b0[2][2], b1[2][2];

  // prologue: stage tile 0 -> buf0
  stage_slot<0, K>(pA, pB, lds, 0, ch0, rsub, koff, lbyte);
  stage_slot<1, K>(pA, pB, lds, 0, ch0, rsub, koff, lbyte);
  stage_slot<2, K>(pA, pB, lds, 0, ch0, rsub, koff, lbyte);
  stage_slot<3, K>(pA, pB, lds, 0, ch0, rsub, koff, lbyte);
  VM4(); BAR();

  for (int T = 0; T < KT - 2; T += 2) {
    ktile<0, K, false>(pA, pB, lds, (T + 1) * 64, ch0, rsub, koff, lbyte,
                       wr, wc, lr, hi, swr, a, b0, b1, acc);
    ktile<1, K, false>(pA, pB, lds, (T + 2) * 64, ch0, rsub, koff, lbyte,
                       wr, wc, lr, hi, swr, a, b0, b1, acc);
  }
  ktile<0, K, false>(pA, pB, lds, (KT - 1) * 64, ch0, rsub, koff, lbyte,
                     wr, wc, lr, hi, swr, a, b0, b1, acc);
  ktile<1, K, true>(pA, pB, lds, 0, ch0, rsub, koff, lbyte,
                    wr, wc, lr, hi, swr, a, b0, b1, acc);
  asm volatile("s_waitcnt vmcnt(0)" ::: "memory");
}

// ---------------------------------------------------------------------------
// GEMM1 (one expert-half, 4 experts, full batch):
//   Hg[m][ee*1024+n] = gates[m][eg0+ee] * relu(x@W1_[eg0+ee] + b1)  (bf16)
// grid = 64mb * 4nb * 4ee = 1024
// ---------------------------------------------------------------------------
__global__ __launch_bounds__(512, 2) void gemm1(
    const u16* __restrict__ xb, const u16* __restrict__ W1t,
    const float* __restrict__ b1, const float* __restrict__ gates,
    u16* __restrict__ Hg, int eg0) {
  __shared__ char lds[131072];
  int t = threadIdx.x;
  int nwg = gridDim.x, cpx = nwg >> 3, bid = blockIdx.x;
  int swz = (bid & 7) * cpx + (bid >> 3);  // bijective XCD swizzle (nwg%8==0)
  int nb = swz & 3, ee = (swz >> 2) & 3, mb = swz >> 4;
  int e = eg0 + ee;

  f32x4 acc[8][4] = {};
  core256<1024>(xb + (size_t)mb * 256 * 1024,
                W1t + ((size_t)e << 20) + (size_t)nb * 256 * 1024,
                lds, t, acc);

  int l = t & 63, w = t >> 6, wr = w >> 2, wc = w & 3, lr = l & 15, hi = l >> 4;
  int m0 = mb * 256 + wr * 128 + hi * 4;
  int n0 = nb * 256 + wc * 64 + lr;
  const float* b1e = b1 + e * OUTD;
#pragma unroll
  for (int m = 0; m < 8; ++m) {
#pragma unroll
    for (int r = 0; r < 4; ++r) {
      int row = m0 + m * 16 + r;
      float g = gates[(size_t)row * NE + e];
#pragma unroll
      for (int nn = 0; nn < 4; ++nn) {
        int n = n0 + nn * 16;
        float v = g * fmaxf(acc[m][nn][r] + b1e[n], 0.f);
        Hg[(size_t)row * KH2 + ee * 1024 + n] = f2bf(v);
      }
    }
  }
}

// ---------------------------------------------------------------------------
// GEMM2 (one expert-half, K=4096):
//   FIRST: out = Hg@W2th + sum_{ee<4} g*b2 ;  else out += same
// grid = 64mb * 4nb = 256  (full chip)
// ---------------------------------------------------------------------------
template <bool FIRST>
__global__ __launch_bounds__(512, 2) void gemm2(
    const u16* __restrict__ Hg, const u16* __restrict__ W2th,
    const float* __restrict__ b2h, const float* __restrict__ gates,
    float* __restrict__ out, int eg0) {
  __shared__ char lds[131072];
  int t = threadIdx.x;
  int nwg = gridDim.x, cpx = nwg >> 3, bid = blockIdx.x;
  int swz = (bid & 7) * cpx + (bid >> 3);
  int nb = swz & 3, mb = swz >> 2;

  f32x4 acc[8][4] = {};
  core256<KH2>(Hg + (size_t)mb * 256 * KH2, W2th + (size_t)nb * 256 * KH2,
               lds, t, acc);

  int l = t & 63, w = t >> 6, wr = w >> 2, wc = w & 3, lr = l & 15, hi = l >> 4;
  int m0 = mb * 256 + wr * 128 + hi * 4;
  int n0 = nb * 256 + wc * 64 + lr;

  float bcol[4][4];
#pragma unroll
  for (int nn = 0; nn < 4; ++nn)
#pragma unroll
    for (int j = 0; j < 4; ++j)
      bcol[nn][j] = b2h[j * OUTD + n0 + nn * 16];

#pragma unroll
  for (int m = 0; m < 8; ++m) {
#pragma unroll
    for (int r = 0; r < 4; ++r) {
      int row = m0 + m * 16 + r;
      float4 ga = *(const float4*)&gates[(size_t)row * NE + eg0];
#pragma unroll
      for (int nn = 0; nn < 4; ++nn) {
        float bias = ga.x * bcol[nn][0] + ga.y * bcol[nn][1] +
                     ga.z * bcol[nn][2] + ga.w * bcol[nn][3];
        size_t oi = (size_t)row * OUTD + n0 + nn * 16;
        float v = acc[m][nn][r] + bias;
        if (FIRST) out[oi] = v;
        else       out[oi] += v;
      }
    }
  }
}

// ---------------------------------------------------------------------------
extern "C" void kernel_launch(void* const* d_in, const int* in_sizes, int n_in,
                              void* d_out, int out_size, void* d_ws, size_t ws_size,
                              hipStream_t stream) {
  (void)in_sizes; (void)n_in; (void)out_size; (void)ws_size;
  const float* text = (const float*)d_in[0];
  const float* tech = (const float*)d_in[1];
  const float* W1   = (const float*)d_in[2];
  const float* b1   = (const float*)d_in[3];
  const float* W2   = (const float*)d_in[4];
  const float* b2   = (const float*)d_in[5];
  const float* Wg   = (const float*)d_in[6];
  const float* bg   = (const float*)d_in[7];
  float* out = (float*)d_out;

  // workspace: 33.5 + 16.8 + 16.8 + 0.5 + 134.2 = 201.85 MB (== round-3 proven)
  char* p = (char*)d_ws;
  u16* xb  = (u16*)p;  p += (size_t)NB * IND * 2;
  u16* W1t = (u16*)p;  p += (size_t)NE * IND * OUTD * 2;
  u16* W2t = (u16*)p;  p += (size_t)NE * OUTD * OUTD * 2;  // 2 halves x [1024][4096]
  float* gates = (float*)p; p += (size_t)NB * NE * 4;
  u16* Hg  = (u16*)p;                                      // [NB][KH2] bf16

  convert_gates<<<dim3(NB / 4), dim3(256), 0, stream>>>(text, tech, Wg, bg, xb, gates);
  transpose_w12<<<dim3(4096), dim3(256), 0, stream>>>(W1, W2, W1t, W2t);

  for (int h = 0; h < 2; ++h) {
    int eg0 = h * 4;
    gemm1<<<dim3(1024), dim3(512), 0, stream>>>(xb, W1t, b1, gates, Hg, eg0);
    const u16* W2th = W2t + ((size_t)h << 22);
    const float* b2h = b2 + (size_t)eg0 * OUTD;
    if (h == 0)
      gemm2<true><<<dim3(256), dim3(512), 0, stream>>>(Hg, W2th, b2h, gates, out, eg0);
    else
      gemm2<false><<<dim3(256), dim3(512), 0, stream>>>(Hg, W2th, b2h, gates, out, eg0);
  }
}

// Round 5
// 603.520 us; speedup vs baseline: 2.5134x; 1.0155x over previous
//
#include <hip/hip_runtime.h>
#include <hip/hip_bf16.h>

// Problem constants
#define NB 16384        // batch rows
#define TEXT_D 768
#define TECH_D 256
#define IND 1024        // IN_D
#define OUTD 1024       // OUT_D
#define NE 8            // experts
#define KH2 4096        // half-hidden K = 4 experts * 1024

typedef unsigned short u16;
typedef __bf16 bf16x8 __attribute__((ext_vector_type(8)));
typedef float f32x4 __attribute__((ext_vector_type(4)));

__device__ __forceinline__ u16 f2bf(float f) {
  union { float f; unsigned int u; } x; x.f = f;
  unsigned int u = x.u;
  return (u16)((u + 0x7FFFu + ((u >> 16) & 1u)) >> 16);
}

__device__ __forceinline__ void gload_lds16(const void* g, void* l) {
  __builtin_amdgcn_global_load_lds(
      (const __attribute__((address_space(1))) unsigned int*)g,
      (__attribute__((address_space(3))) unsigned int*)l, 16, 0, 0);
}

// ---------------------------------------------------------------------------
// Fused: concat->bf16 xb  AND  gates = softmax(x@Wg + bg).
// ---------------------------------------------------------------------------
__global__ __launch_bounds__(256) void convert_gates(
    const float* __restrict__ text, const float* __restrict__ tech,
    const float* __restrict__ Wg, const float* __restrict__ bg,
    u16* __restrict__ xb, float* __restrict__ gates) {
  int t = threadIdx.x;
  int wave = t >> 6, lane = t & 63;
  int row = blockIdx.x * 4 + wave;

  float acc[NE];
#pragma unroll
  for (int e = 0; e < NE; ++e) acc[e] = 0.f;

#pragma unroll
  for (int j = 0; j < 4; ++j) {
    int col = j * 256 + lane * 4;
    float4 v = (j < 3) ? *(const float4*)&text[(size_t)row * TEXT_D + col]
                       : *(const float4*)&tech[(size_t)row * TECH_D + lane * 4];
    ushort4 o = make_ushort4(f2bf(v.x), f2bf(v.y), f2bf(v.z), f2bf(v.w));
    *(ushort4*)&xb[(size_t)row * IND + col] = o;
    const float* wp = &Wg[(size_t)col * NE];
    float xv[4] = {v.x, v.y, v.z, v.w};
#pragma unroll
    for (int i = 0; i < 4; ++i) {
      float4 w0 = *(const float4*)&wp[i * NE];
      float4 w1 = *(const float4*)&wp[i * NE + 4];
      acc[0] = fmaf(xv[i], w0.x, acc[0]);
      acc[1] = fmaf(xv[i], w0.y, acc[1]);
      acc[2] = fmaf(xv[i], w0.z, acc[2]);
      acc[3] = fmaf(xv[i], w0.w, acc[3]);
      acc[4] = fmaf(xv[i], w1.x, acc[4]);
      acc[5] = fmaf(xv[i], w1.y, acc[5]);
      acc[6] = fmaf(xv[i], w1.z, acc[6]);
      acc[7] = fmaf(xv[i], w1.w, acc[7]);
    }
  }
#pragma unroll
  for (int off = 32; off; off >>= 1)
#pragma unroll
    for (int e = 0; e < NE; ++e) acc[e] += __shfl_xor(acc[e], off);

#pragma unroll
  for (int e = 0; e < NE; ++e) acc[e] += bg[e];
  float mx = acc[0];
#pragma unroll
  for (int e = 1; e < NE; ++e) mx = fmaxf(mx, acc[e]);
  float s = 0.f;
#pragma unroll
  for (int e = 0; e < NE; ++e) { acc[e] = expf(acc[e] - mx); s += acc[e]; }
  float inv = 1.f / s;
  if (lane < NE) gates[(size_t)row * NE + lane] = acc[lane] * inv;
}

// ---------------------------------------------------------------------------
// Transpose fp32 W -> bf16, both weights in one dispatch.
//   blocks [0,2048):   W1[e][k][n] -> W1t[e][n*1024 + k]
//   blocks [2048,4096): W2[e][k][n] -> W2t[e>>2][n*4096 + (e&3)*1024 + k]
// ---------------------------------------------------------------------------
__global__ __launch_bounds__(256) void transpose_w12(
    const float* __restrict__ W1, const float* __restrict__ W2,
    u16* __restrict__ W1t, u16* __restrict__ W2t) {
  __shared__ u16 tile[64][65];
  int bid = blockIdx.x;
  int half = bid >> 11;
  int b2 = bid & 2047;
  int e = b2 >> 8;
  int tb = b2 & 255;
  int r0 = (tb >> 4) * 64;     // input row block (k)
  int c0 = (tb & 15) * 64;     // input col block (n)
  const float* We; u16* Wte; int ostride;
  if (half == 0) {
    We = W1 + (size_t)e * IND * OUTD;
    Wte = W1t + ((size_t)e << 20);
    ostride = 1024;
  } else {
    We = W2 + (size_t)e * IND * OUTD;
    Wte = W2t + ((size_t)(e >> 2) << 22) + (size_t)(e & 3) * 1024;
    ostride = KH2;
  }
  int t = threadIdx.x;
  int tr = t >> 4;
  int tc = (t & 15) * 4;
#pragma unroll
  for (int j = 0; j < 4; ++j) {
    int row = j * 16 + tr;
    float4 v = *(const float4*)&We[(size_t)(r0 + row) * OUTD + c0 + tc];
    tile[row][tc + 0] = f2bf(v.x);
    tile[row][tc + 1] = f2bf(v.y);
    tile[row][tc + 2] = f2bf(v.z);
    tile[row][tc + 3] = f2bf(v.w);
  }
  __syncthreads();
#pragma unroll
  for (int j = 0; j < 4; ++j) {
    int row = j * 16 + tr;     // output row (= input col n)
    ushort4 o = make_ushort4(tile[tc + 0][row], tile[tc + 1][row],
                             tile[tc + 2][row], tile[tc + 3][row]);
    *(ushort4*)&Wte[(size_t)(c0 + row) * ostride + r0 + tc] = o;
  }
}

// ---------------------------------------------------------------------------
// 256x256 8-phase GEMM core (BK=64, 8 waves 2x4, 128 KiB LDS).
// XOR-swizzled both-sides (linear gload_lds dest, pre-swizzled src, XOR read).
// Half-tiles: H0 = slots{0:A rows 0-63/128-191, 1:B lo} (read ph1),
//             H1 = slots{2:B hi, 3:A rows 64-127/192-255} (read ph2/ph3).
// Deep pipeline (T4): ph1(T) issues H1(T+1)->other buf; ph4(T) issues
// H0(T+2)->CURRENT buf (reads of it finished at ph3, barrier-protected).
// Waits: vmcnt(8) end-ph1 (guarantees H1(T)); vmcnt(8) end-ph4 (guarantees
// H0(T+1)). 8-12 loads in flight; each load has ~4 phases to land.
// Epilogue: penultimate tile vmcnt(8)/vmcnt(4); last tile vmcnt(0).
// ---------------------------------------------------------------------------
#define BAR() asm volatile("s_barrier" ::: "memory")
#define VM0() asm volatile("s_waitcnt vmcnt(0)" ::: "memory")
#define VM4() asm volatile("s_waitcnt vmcnt(4)" ::: "memory")
#define VM8() asm volatile("s_waitcnt vmcnt(8)" ::: "memory")

template <int SLOT, int K>
__device__ __forceinline__ void stage_slot(
    const u16* __restrict__ pA, const u16* __restrict__ pB, char* sb, int k0,
    int ch0, int rsub, int koff, int lbyte) {
#pragma unroll
  for (int j = 0; j < 2; ++j) {
    int ch = ch0 + j;
    int r;
    if constexpr (SLOT == 0)      r = (ch >> 3) * 128 + (ch & 7) * 8 + rsub;
    else if constexpr (SLOT == 3) r = 64 + (ch >> 3) * 128 + (ch & 7) * 8 + rsub;
    else if constexpr (SLOT == 1) r = (ch >> 2) * 64 + (ch & 3) * 8 + rsub;
    else                          r = (ch >> 2) * 64 + 32 + (ch & 3) * 8 + rsub;
    const u16* g = (SLOT == 0 || SLOT == 3) ? pA : pB;
    char* lb = sb + ((SLOT == 0 || SLOT == 3) ? 0 : 32768) + r * 128 + lbyte;
    gload_lds16(g + (size_t)r * K + k0 + koff, lb);
  }
}

template <int QH>
__device__ __forceinline__ void load_a(const char* rb, int wr, int lr, int hi,
                                       int swr, bf16x8 (&a)[4][2]) {
#pragma unroll
  for (int i = 0; i < 4; ++i)
#pragma unroll
    for (int ks = 0; ks < 2; ++ks)
      a[i][ks] = *(const bf16x8*)(rb + (wr * 128 + QH * 64 + i * 16 + lr) * 128
                                  + ((ks * 64 + hi * 16) ^ swr));
}

template <int NH>
__device__ __forceinline__ void load_b(const char* rb, int wc, int lr, int hi,
                                       int swr, bf16x8 (&b)[2][2]) {
#pragma unroll
  for (int q = 0; q < 2; ++q)
#pragma unroll
    for (int ks = 0; ks < 2; ++ks)
      b[q][ks] = *(const bf16x8*)(rb + 32768 +
                                  (wc * 64 + (NH * 2 + q) * 16 + lr) * 128
                                  + ((ks * 64 + hi * 16) ^ swr));
}

template <int MH, int NH>
__device__ __forceinline__ void mfma_quad(const bf16x8 (&a)[4][2],
                                          const bf16x8 (&b)[2][2],
                                          f32x4 (&acc)[8][4]) {
  __builtin_amdgcn_s_setprio(1);
#pragma unroll
  for (int i = 0; i < 4; ++i)
#pragma unroll
    for (int q = 0; q < 2; ++q) {
      acc[MH*4+i][NH*2+q] = __builtin_amdgcn_mfma_f32_16x16x32_bf16(
          a[i][0], b[q][0], acc[MH*4+i][NH*2+q], 0, 0, 0);
      acc[MH*4+i][NH*2+q] = __builtin_amdgcn_mfma_f32_16x16x32_bf16(
          a[i][1], b[q][1], acc[MH*4+i][NH*2+q], 0, 0, 0);
    }
  __builtin_amdgcn_s_setprio(0);
}

// MODE: 0 = steady, 1 = penultimate (no ph4 stage), 2 = last (no stages)
template <int RB, int K, int MODE>
__device__ __forceinline__ void ktile(
    const u16* __restrict__ pA, const u16* __restrict__ pB, char* lds,
    int kH1, int kH0, int ch0, int rsub, int koff, int lbyte,
    int wr, int wc, int lr, int hi, int swr,
    bf16x8 (&a)[4][2], bf16x8 (&b0)[2][2], bf16x8 (&b1)[2][2],
    f32x4 (&acc)[8][4]) {
  const char* rb = lds + RB * 65536;
  char* nbuf = lds + (RB ^ 1) * 65536;  // tile T+1's buffer
  char* tbuf = lds + RB * 65536;        // tile T+2's buffer (this one)
  // ph1: read H0(T); issue H1(T+1)
  load_a<0>(rb, wr, lr, hi, swr, a);
  load_b<0>(rb, wc, lr, hi, swr, b0);
  if constexpr (MODE < 2) {
    stage_slot<2, K>(pA, pB, nbuf, kH1, ch0, rsub, koff, lbyte);
    stage_slot<3, K>(pA, pB, nbuf, kH1, ch0, rsub, koff, lbyte);
  }
  BAR();
  mfma_quad<0, 0>(a, b0, acc);
  if constexpr (MODE == 2) { VM0(); } else { VM8(); }  // H1(T) ready
  BAR();
  // ph2: read b1 (H1 slot2)
  load_b<1>(rb, wc, lr, hi, swr, b1);
  BAR();
  mfma_quad<0, 1>(a, b1, acc);
  BAR();
  // ph3: read a1 (H1 slot3)
  load_a<1>(rb, wr, lr, hi, swr, a);
  BAR();
  mfma_quad<1, 0>(a, b0, acc);
  BAR();
  // ph4: issue H0(T+2) into current buf (its reads completed at ph3)
  if constexpr (MODE == 0) {
    stage_slot<0, K>(pA, pB, tbuf, kH0, ch0, rsub, koff, lbyte);
    stage_slot<1, K>(pA, pB, tbuf, kH0, ch0, rsub, koff, lbyte);
  }
  BAR();
  mfma_quad<1, 1>(a, b1, acc);
  if constexpr (MODE == 0) { VM8(); }       // H0(T+1) ready
  else if constexpr (MODE == 1) { VM4(); }  // H0(KT-1) ready (no H0(KT) issued)
  BAR();
}

template <int K>
__device__ __forceinline__ void core256(const u16* __restrict__ pA,
                                        const u16* __restrict__ pB,
                                        char* lds, int t, f32x4 (&acc)[8][4]) {
  constexpr int KT = K / 64;
  static_assert(KT >= 4 && (KT & 1) == 0, "KT must be even >= 4");
  const int l = t & 63;
  const int w = t >> 6;
  const int wr = w >> 2, wc = w & 3;
  const int lr = l & 15, hi = l >> 4;
  const int rsub = l >> 3;
  const int koff = ((l & 7) ^ rsub) << 3;  // pre-swizzled source col (elems)
  const int lbyte = (l & 7) * 16;
  const int ch0 = w * 2;
  const int swr = (lr & 7) << 4;           // read-side swizzle (bytes)

  bf16x8 a[4][2], b0[2][2], b1[2][2];

  // prologue: H0(0), H1(0) -> buf0; H0(1) -> buf1; need H0(0) -> vmcnt(8)
  stage_slot<0, K>(pA, pB, lds, 0, ch0, rsub, koff, lbyte);
  stage_slot<1, K>(pA, pB, lds, 0, ch0, rsub, koff, lbyte);
  stage_slot<2, K>(pA, pB, lds, 0, ch0, rsub, koff, lbyte);
  stage_slot<3, K>(pA, pB, lds, 0, ch0, rsub, koff, lbyte);
  stage_slot<0, K>(pA, pB, lds + 65536, 64, ch0, rsub, koff, lbyte);
  stage_slot<1, K>(pA, pB, lds + 65536, 64, ch0, rsub, koff, lbyte);
  VM8(); BAR();

  for (int T = 0; T < KT - 2; T += 2) {
    ktile<0, K, 0>(pA, pB, lds, (T + 1) * 64, (T + 2) * 64, ch0, rsub, koff,
                   lbyte, wr, wc, lr, hi, swr, a, b0, b1, acc);
    ktile<1, K, 0>(pA, pB, lds, (T + 2) * 64, (T + 3) * 64, ch0, rsub, koff,
                   lbyte, wr, wc, lr, hi, swr, a, b0, b1, acc);
  }
  ktile<0, K, 1>(pA, pB, lds, (KT - 1) * 64, 0, ch0, rsub, koff,
                 lbyte, wr, wc, lr, hi, swr, a, b0, b1, acc);
  ktile<1, K, 2>(pA, pB, lds, 0, 0, ch0, rsub, koff,
                 lbyte, wr, wc, lr, hi, swr, a, b0, b1, acc);
  VM0();
}

// ---------------------------------------------------------------------------
// GEMM1 (one expert-half, 4 experts, full batch):
//   Hg[m][ee*1024+n] = gates[m][eg0+ee] * relu(x@W1_[eg0+ee] + b1)  (bf16)
// grid = 64mb * 4nb * 4ee = 1024
// ---------------------------------------------------------------------------
__global__ __launch_bounds__(512, 2) void gemm1(
    const u16* __restrict__ xb, const u16* __restrict__ W1t,
    const float* __restrict__ b1, const float* __restrict__ gates,
    u16* __restrict__ Hg, int eg0) {
  __shared__ char lds[131072];
  int t = threadIdx.x;
  int nwg = gridDim.x, cpx = nwg >> 3, bid = blockIdx.x;
  int swz = (bid & 7) * cpx + (bid >> 3);  // bijective XCD swizzle (nwg%8==0)
  int nb = swz & 3, ee = (swz >> 2) & 3, mb = swz >> 4;
  int e = eg0 + ee;

  f32x4 acc[8][4] = {};
  core256<1024>(xb + (size_t)mb * 256 * 1024,
                W1t + ((size_t)e << 20) + (size_t)nb * 256 * 1024,
                lds, t, acc);

  int l = t & 63, w = t >> 6, wr = w >> 2, wc = w & 3, lr = l & 15, hi = l >> 4;
  int m0 = mb * 256 + wr * 128 + hi * 4;
  int n0 = nb * 256 + wc * 64 + lr;
  const float* b1e = b1 + e * OUTD;
#pragma unroll
  for (int m = 0; m < 8; ++m) {
#pragma unroll
    for (int r = 0; r < 4; ++r) {
      int row = m0 + m * 16 + r;
      float g = gates[(size_t)row * NE + e];
#pragma unroll
      for (int nn = 0; nn < 4; ++nn) {
        int n = n0 + nn * 16;
        float v = g * fmaxf(acc[m][nn][r] + b1e[n], 0.f);
        Hg[(size_t)row * KH2 + ee * 1024 + n] = f2bf(v);
      }
    }
  }
}

// ---------------------------------------------------------------------------
// GEMM2 (one expert-half, K=4096):
//   FIRST: out = Hg@W2th + sum_{ee<4} g*b2 ;  else out += same
// grid = 64mb * 4nb = 256  (full chip)
// ---------------------------------------------------------------------------
template <bool FIRST>
__global__ __launch_bounds__(512, 2) void gemm2(
    const u16* __restrict__ Hg, const u16* __restrict__ W2th,
    const float* __restrict__ b2h, const float* __restrict__ gates,
    float* __restrict__ out, int eg0) {
  __shared__ char lds[131072];
  int t = threadIdx.x;
  int nwg = gridDim.x, cpx = nwg >> 3, bid = blockIdx.x;
  int swz = (bid & 7) * cpx + (bid >> 3);
  int nb = swz & 3, mb = swz >> 2;

  f32x4 acc[8][4] = {};
  core256<KH2>(Hg + (size_t)mb * 256 * KH2, W2th + (size_t)nb * 256 * KH2,
               lds, t, acc);

  int l = t & 63, w = t >> 6, wr = w >> 2, wc = w & 3, lr = l & 15, hi = l >> 4;
  int m0 = mb * 256 + wr * 128 + hi * 4;
  int n0 = nb * 256 + wc * 64 + lr;

  float bcol[4][4];
#pragma unroll
  for (int nn = 0; nn < 4; ++nn)
#pragma unroll
    for (int j = 0; j < 4; ++j)
      bcol[nn][j] = b2h[j * OUTD + n0 + nn * 16];

#pragma unroll
  for (int m = 0; m < 8; ++m) {
#pragma unroll
    for (int r = 0; r < 4; ++r) {
      int row = m0 + m * 16 + r;
      float4 ga = *(const float4*)&gates[(size_t)row * NE + eg0];
#pragma unroll
      for (int nn = 0; nn < 4; ++nn) {
        float bias = ga.x * bcol[nn][0] + ga.y * bcol[nn][1] +
                     ga.z * bcol[nn][2] + ga.w * bcol[nn][3];
        size_t oi = (size_t)row * OUTD + n0 + nn * 16;
        float v = acc[m][nn][r] + bias;
        if (FIRST) out[oi] = v;
        else       out[oi] += v;
      }
    }
  }
}

// ---------------------------------------------------------------------------
extern "C" void kernel_launch(void* const* d_in, const int* in_sizes, int n_in,
                              void* d_out, int out_size, void* d_ws, size_t ws_size,
                              hipStream_t stream) {
  (void)in_sizes; (void)n_in; (void)out_size; (void)ws_size;
  const float* text = (const float*)d_in[0];
  const float* tech = (const float*)d_in[1];
  const float* W1   = (const float*)d_in[2];
  const float* b1   = (const float*)d_in[3];
  const float* W2   = (const float*)d_in[4];
  const float* b2   = (const float*)d_in[5];
  const float* Wg   = (const float*)d_in[6];
  const float* bg   = (const float*)d_in[7];
  float* out = (float*)d_out;

  // workspace: 33.5 + 16.8 + 16.8 + 0.5 + 134.2 = 201.85 MB (proven fits)
  char* p = (char*)d_ws;
  u16* xb  = (u16*)p;  p += (size_t)NB * IND * 2;
  u16* W1t = (u16*)p;  p += (size_t)NE * IND * OUTD * 2;
  u16* W2t = (u16*)p;  p += (size_t)NE * OUTD * OUTD * 2;  // 2 halves x [1024][4096]
  float* gates = (float*)p; p += (size_t)NB * NE * 4;
  u16* Hg  = (u16*)p;                                      // [NB][KH2] bf16

  convert_gates<<<dim3(NB / 4), dim3(256), 0, stream>>>(text, tech, Wg, bg, xb, gates);
  transpose_w12<<<dim3(4096), dim3(256), 0, stream>>>(W1, W2, W1t, W2t);

  for (int h = 0; h < 2; ++h) {
    int eg0 = h * 4;
    gemm1<<<dim3(1024), dim3(512), 0, stream>>>(xb, W1t, b1, gates, Hg, eg0);
    const u16* W2th = W2t + ((size_t)h << 22);
    const float* b2h = b2 + (size_t)eg0 * OUTD;
    if (h == 0)
      gemm2<true><<<dim3(256), dim3(512), 0, stream>>>(Hg, W2th, b2h, gates, out, eg0);
    else
      gemm2<false><<<dim3(256), dim3(512), 0, stream>>>(Hg, W2th, b2h, gates, out, eg0);
  }
}